// Round 5
// baseline (426.093 us; speedup 1.0000x reference)
//
#include <hip/hip_runtime.h>
#include <hip/hip_bf16.h>

using bf16 = __hip_bfloat16;
using bf16x8 = __attribute__((ext_vector_type(8))) short;
using f32x4  = __attribute__((ext_vector_type(4))) float;

__device__ inline unsigned short f2bu(float f){ bf16 h = __float2bfloat16(f); return *(unsigned short*)&h; }

constexpr int D_ = 1024, L_ = 2048;
constexpr int CN = 384;   // Cbig row stride (floats)

// ---------------------------------------------------------------------------
// q[e] = bq[e] + sum_d cq[d]*wq[e,d]
__global__ __launch_bounds__(256) void k_q(const float* __restrict__ cq, const float* __restrict__ wq,
                                           const float* __restrict__ bq, float* __restrict__ q){
  int e = blockIdx.x*256 + threadIdx.x;
  const float* wr = wq + (size_t)e*D_;
  float acc = bq[e];
  for (int dd=0; dd<D_; dd+=8){
    float4 a0 = *(const float4*)(wr+dd), a1 = *(const float4*)(wr+dd+4);
    float4 c0 = *(const float4*)(cq+dd), c1 = *(const float4*)(cq+dd+4);
    acc += a0.x*c0.x + a0.y*c0.y + a0.z*c0.z + a0.w*c0.w
         + a1.x*c1.x + a1.y*c1.y + a1.z*c1.z + a1.w*c1.w;
  }
  q[e] = acc;
}

// qwk[hh][d] = sum_e q[hh*64+e]*wk[hh*64+e, d]
__global__ __launch_bounds__(256) void k_qwk(const float* __restrict__ q, const float* __restrict__ wk,
                                             float* __restrict__ qwk){
  int idx = blockIdx.x*256 + threadIdx.x;
  int hh = idx >> 10, d = idx & 1023;
  float acc = 0.f;
  for (int e=0;e<64;++e)
    acc += q[hh*64+e]*wk[(size_t)(hh*64+e)*D_ + d];
  qwk[idx] = acc;
}

// fp32 -> bf16 bulk convert (4 elems/thread), optional scale
__global__ __launch_bounds__(256) void k_cvt(const float* __restrict__ in, unsigned short* __restrict__ outp,
                                             float scale){
  int i = blockIdx.x*256 + threadIdx.x;
  float4 v = *(const float4*)(in + (size_t)4*i);
  *(ushort4*)(outp + (size_t)4*i) = make_ushort4(f2bu(v.x*scale), f2bu(v.y*scale),
                                                 f2bu(v.z*scale), f2bu(v.w*scale));
}

// transpose + convert: outp[dd][d] = bf16(in[d][dd])   (for wv^T)
__global__ __launch_bounds__(256) void k_tc(const float* __restrict__ in, unsigned short* __restrict__ outp){
  __shared__ float t[64][68];
  const int tid = threadIdx.x;
  const int r = tid >> 2, c0 = (tid & 3)*16;
  const int d0 = blockIdx.y*64, dd0 = blockIdx.x*64;
  #pragma unroll
  for (int j=0;j<4;++j){
    float4 v = *(const float4*)(in + (size_t)(d0+r)*D_ + dd0 + c0 + 4*j);
    t[r][c0+4*j+0] = v.x; t[r][c0+4*j+1] = v.y; t[r][c0+4*j+2] = v.z; t[r][c0+4*j+3] = v.w;
  }
  __syncthreads();
  #pragma unroll
  for (int j=0;j<4;++j){
    ushort4 o = make_ushort4(f2bu(t[c0+4*j+0][r]), f2bu(t[c0+4*j+1][r]),
                             f2bu(t[c0+4*j+2][r]), f2bu(t[c0+4*j+3][r]));
    *(ushort4*)(outp + (size_t)(dd0+r)*D_ + d0 + c0 + 4*j) = o;
  }
}

// ---------------------------------------------------------------------------
// Build Btb [384][1024] bf16: rows v*16+k = proj_w[v][dd][k] (transposed);
// rows 256+v = proj_b[v]+ce[v]. grid (16 ddchunk, 16 v).
__global__ __launch_bounds__(256) void k_tpB(const float* __restrict__ proj_w, const float* __restrict__ proj_b,
                                             const float* __restrict__ ce, unsigned short* __restrict__ Btb){
  __shared__ float t[64][17];
  const int tid = threadIdx.x;
  const int v = blockIdx.y, dd0 = blockIdx.x*64;
  { const int r = tid >> 2, kq = tid & 3;
    float4 a = *(const float4*)(proj_w + ((size_t)(v*D_ + dd0 + r))*16 + kq*4);
    t[r][kq*4+0]=a.x; t[r][kq*4+1]=a.y; t[r][kq*4+2]=a.z; t[r][kq*4+3]=a.w; }
  __syncthreads();
  { const int k = tid >> 4, c0 = (tid & 15)*4;
    ushort4 o = make_ushort4(f2bu(t[c0+0][k]), f2bu(t[c0+1][k]), f2bu(t[c0+2][k]), f2bu(t[c0+3][k]));
    *(ushort4*)(Btb + (size_t)(v*16+k)*D_ + dd0 + c0) = o; }
  if (tid < 16){
    const int c0 = tid*4;
    float4 pb = *(const float4*)(proj_b + v*D_ + dd0 + c0);
    float4 cc = *(const float4*)(ce     + v*D_ + dd0 + c0);
    ushort4 o = make_ushort4(f2bu(pb.x+cc.x), f2bu(pb.y+cc.y), f2bu(pb.z+cc.z), f2bu(pb.w+cc.w));
    *(ushort4*)(Btb + (size_t)(256+v)*D_ + dd0 + c0) = o;
  }
}

// ---------------------------------------------------------------------------
// big precompute GEMM: C[row][col] fp32 = A(bf16)[1152][1024] · Bt(bf16)[384][1024]^T
// rows >= Mvalid not written. grid (3, 9), 4 waves.
__global__ __launch_bounds__(256) void k_gemm_big(const unsigned short* __restrict__ A,
                                                  const unsigned short* __restrict__ Bt,
                                                  float* __restrict__ C, int Mvalid){
  __shared__ unsigned short As[128][40];
  __shared__ unsigned short Bs[128][40];
  const int tid = threadIdx.x;
  const int wave = tid >> 6, lane = tid & 63;
  const int wm = wave & 1, wn = wave >> 1;
  const int m0 = blockIdx.y*128, n0 = blockIdx.x*128;
  const int lm = lane & 15, kg = lane >> 4;
  f32x4 acc[4][4];
  #pragma unroll
  for (int mf=0;mf<4;++mf)
    #pragma unroll
    for (int nf=0;nf<4;++nf)
      acc[mf][nf] = (f32x4){0.f,0.f,0.f,0.f};
  for (int k0=0; k0<D_; k0+=32){
    #pragma unroll
    for (int i=0;i<2;++i){
      int s = tid + 256*i;
      int row = s >> 2, col = (s & 3)*8;
      *(uint4*)(&As[row][col]) = *(const uint4*)(A  + (size_t)(m0+row)*D_ + k0 + col);
      *(uint4*)(&Bs[row][col]) = *(const uint4*)(Bt + (size_t)(n0+row)*D_ + k0 + col);
    }
    __syncthreads();
    bf16x8 af[4], bfr[4];
    #pragma unroll
    for (int f=0;f<4;++f){
      af[f]  = *(const bf16x8*)(&As[wm*64 + f*16 + lm][kg*8]);
      bfr[f] = *(const bf16x8*)(&Bs[wn*64 + f*16 + lm][kg*8]);
    }
    #pragma unroll
    for (int mf=0;mf<4;++mf)
      #pragma unroll
      for (int nf=0;nf<4;++nf)
        acc[mf][nf] = __builtin_amdgcn_mfma_f32_16x16x32_bf16(af[mf], bfr[nf], acc[mf][nf], 0,0,0);
    __syncthreads();
  }
  #pragma unroll
  for (int nf=0;nf<4;++nf){
    int col = n0 + wn*64 + nf*16 + lm;
    #pragma unroll
    for (int mf=0;mf<4;++mf)
      #pragma unroll
      for (int r=0;r<4;++r){
        int row = m0 + wm*64 + mf*16 + kg*4 + r;
        if (row < Mvalid) C[(size_t)row*CN + col] = acc[mf][nf][r];
      }
  }
}

// ---------------------------------------------------------------------------
// W2 GEMM: C(bf16)[1024][1024] = A(fp32 wo)[1024][1024] · Bt(bf16 wv^T)[1024][1024]^T
__global__ __launch_bounds__(256) void k_gemm_fb(const float* __restrict__ A,
                                                 const unsigned short* __restrict__ Bt,
                                                 unsigned short* __restrict__ C){
  __shared__ unsigned short As[128][40];
  __shared__ unsigned short Bs[128][40];
  const int tid = threadIdx.x;
  const int wave = tid >> 6, lane = tid & 63;
  const int wm = wave & 1, wn = wave >> 1;
  const int m0 = blockIdx.y*128, n0 = blockIdx.x*128;
  const int lm = lane & 15, kg = lane >> 4;
  f32x4 acc[4][4];
  #pragma unroll
  for (int mf=0;mf<4;++mf)
    #pragma unroll
    for (int nf=0;nf<4;++nf)
      acc[mf][nf] = (f32x4){0.f,0.f,0.f,0.f};
  for (int k0=0; k0<D_; k0+=32){
    #pragma unroll
    for (int i=0;i<4;++i){
      int s = tid + 256*i;
      int row = s >> 3, col = (s & 7)*4;
      float4 av = *(const float4*)(A + (size_t)(m0+row)*D_ + k0 + col);
      *(ushort4*)(&As[row][col]) = make_ushort4(f2bu(av.x), f2bu(av.y), f2bu(av.z), f2bu(av.w));
    }
    #pragma unroll
    for (int i=0;i<2;++i){
      int s = tid + 256*i;
      int row = s >> 2, col = (s & 3)*8;
      *(uint4*)(&Bs[row][col]) = *(const uint4*)(Bt + (size_t)(n0+row)*D_ + k0 + col);
    }
    __syncthreads();
    bf16x8 af[4], bfr[4];
    #pragma unroll
    for (int f=0;f<4;++f){
      af[f]  = *(const bf16x8*)(&As[wm*64 + f*16 + lm][kg*8]);
      bfr[f] = *(const bf16x8*)(&Bs[wn*64 + f*16 + lm][kg*8]);
    }
    #pragma unroll
    for (int mf=0;mf<4;++mf)
      #pragma unroll
      for (int nf=0;nf<4;++nf)
        acc[mf][nf] = __builtin_amdgcn_mfma_f32_16x16x32_bf16(af[mf], bfr[nf], acc[mf][nf], 0,0,0);
    __syncthreads();
  }
  #pragma unroll
  for (int nf=0;nf<4;++nf){
    int col = n0 + wn*64 + nf*16 + lm;
    #pragma unroll
    for (int mf=0;mf<4;++mf)
      #pragma unroll
      for (int r=0;r<4;++r){
        int row = m0 + wm*64 + mf*16 + kg*4 + r;
        C[(size_t)row*D_ + col] = f2bu(acc[mf][nf][r]);
      }
  }
}

// ---------------------------------------------------------------------------
// out GEMM: C fp32 = A1(bf16 ctx)[M][1024]·B1(fp32 wo)^T + A2(fp32 pe)[M][1024]·B2(bf16 W2)^T + bias
__global__ __launch_bounds__(256) void k_gemm_cat3(const unsigned short* __restrict__ A1,
                                                   const float* __restrict__ B1,
                                                   const float* __restrict__ A2,
                                                   const unsigned short* __restrict__ B2,
                                                   const float* __restrict__ bias, float* __restrict__ C){
  __shared__ unsigned short As[128][40];
  __shared__ unsigned short Bs[128][40];
  const int tid = threadIdx.x;
  const int wave = tid >> 6, lane = tid & 63;
  const int wm = wave & 1, wn = wave >> 1;
  const int m0 = blockIdx.y*128, n0 = blockIdx.x*128;
  const int lm = lane & 15, kg = lane >> 4;
  f32x4 acc[4][4];
  #pragma unroll
  for (int mf=0;mf<4;++mf)
    #pragma unroll
    for (int nf=0;nf<4;++nf)
      acc[mf][nf] = (f32x4){0.f,0.f,0.f,0.f};
  for (int k0=0; k0<2048; k0+=32){
    if (k0 < D_){
      #pragma unroll
      for (int i=0;i<2;++i){
        int s = tid + 256*i;
        int row = s >> 2, col = (s & 3)*8;
        *(uint4*)(&As[row][col]) = *(const uint4*)(A1 + (size_t)(m0+row)*D_ + k0 + col);
      }
      #pragma unroll
      for (int i=0;i<4;++i){
        int s = tid + 256*i;
        int row = s >> 3, col = (s & 7)*4;
        float4 bv4 = *(const float4*)(B1 + (size_t)(n0+row)*D_ + k0 + col);
        *(ushort4*)(&Bs[row][col]) = make_ushort4(f2bu(bv4.x), f2bu(bv4.y), f2bu(bv4.z), f2bu(bv4.w));
      }
    } else {
      int kk = k0 - D_;
      #pragma unroll
      for (int i=0;i<4;++i){
        int s = tid + 256*i;
        int row = s >> 3, col = (s & 7)*4;
        float4 av = *(const float4*)(A2 + (size_t)(m0+row)*D_ + kk + col);
        *(ushort4*)(&As[row][col]) = make_ushort4(f2bu(av.x), f2bu(av.y), f2bu(av.z), f2bu(av.w));
      }
      #pragma unroll
      for (int i=0;i<2;++i){
        int s = tid + 256*i;
        int row = s >> 2, col = (s & 3)*8;
        *(uint4*)(&Bs[row][col]) = *(const uint4*)(B2 + (size_t)(n0+row)*D_ + kk + col);
      }
    }
    __syncthreads();
    bf16x8 af[4], bfr[4];
    #pragma unroll
    for (int f=0;f<4;++f){
      af[f]  = *(const bf16x8*)(&As[wm*64 + f*16 + lm][kg*8]);
      bfr[f] = *(const bf16x8*)(&Bs[wn*64 + f*16 + lm][kg*8]);
    }
    #pragma unroll
    for (int mf=0;mf<4;++mf)
      #pragma unroll
      for (int nf=0;nf<4;++nf)
        acc[mf][nf] = __builtin_amdgcn_mfma_f32_16x16x32_bf16(af[mf], bfr[nf], acc[mf][nf], 0,0,0);
    __syncthreads();
  }
  #pragma unroll
  for (int nf=0;nf<4;++nf){
    int col = n0 + wn*64 + nf*16 + lm;
    float bval = bias[col];
    #pragma unroll
    for (int mf=0;mf<4;++mf)
      #pragma unroll
      for (int r=0;r<4;++r){
        int row = m0 + wm*64 + mf*16 + kg*4 + r;
        C[(size_t)row*D_ + col] = acc[mf][nf][r] + bval;
      }
  }
}

// ---------------------------------------------------------------------------
// fused per-batch: patches -> scores -> softmax -> ctx0 (bf16, 2048x1024)
// reads Cbig: row d (0..1023): [v*16+k]=wvp, [256+v]=wvc-part; row 1024+hh: qwkp/qwkc (prescaled)
__global__ __launch_bounds__(256) void k_fused3(const float* __restrict__ x, int bb,
                                                const float* __restrict__ Cbig, const float* __restrict__ bv,
                                                unsigned short* __restrict__ ctx){
  __shared__ float patchL[16][16][16];  // [s][v][k]
  __shared__ float attnL[16][16][16];   // [s][hh][v]
  const int tid = threadIdx.x;
  const int sg = blockIdx.x >> 2;
  const int dc = blockIdx.x & 3;
  { // phase A: load patches (thread = (s, v))
    const int s = tid >> 4, v = tid & 15;
    const int l = sg*16 + s;
    const int hi = l >> 6, wi = l & 63;
    const float* xp = x + ((size_t)((bb*16+v)*128 + hi*4)*256 + wi*4);
    #pragma unroll
    for (int pi=0; pi<4; ++pi){
      float4 r = *(const float4*)(xp + pi*256);
      patchL[s][v][pi*4+0] = r.x; patchL[s][v][pi*4+1] = r.y;
      patchL[s][v][pi*4+2] = r.z; patchL[s][v][pi*4+3] = r.w;
    }
  }
  __syncthreads();
  { // phase B: scores + softmax (thread = (s, hh))
    const int s = tid >> 4, hh = tid & 15;
    const float* qrow = Cbig + (size_t)(1024+hh)*CN;
    float sc[16];
    #pragma unroll
    for (int v=0; v<16; ++v){
      float a = qrow[256+v];
      const float* qp = qrow + v*16;
      #pragma unroll
      for (int k=0;k<16;++k) a += qp[k]*patchL[s][v][k];
      sc[v] = a;
    }
    float mx = sc[0];
    #pragma unroll
    for (int v=1;v<16;++v) mx = fmaxf(mx, sc[v]);
    float sum = 0.f;
    #pragma unroll
    for (int v=0;v<16;++v){ sc[v] = __expf(sc[v]-mx); sum += sc[v]; }
    float inv = 1.f/sum;
    #pragma unroll
    for (int v=0;v<16;++v) attnL[s][hh][v] = sc[v]*inv;
  }
  __syncthreads();
  // phase C: ctx0[s][d] = sum_v attn[s,hh,v]*(wvp[v,d,:]·patch[s,v,:] + wvc[v,d])
  const int d = dc*256 + tid;
  const int hh = d >> 6;
  const int l0 = sg*16;
  const float* crow = Cbig + (size_t)d*CN;
  const float bvd = bv[d];
  float acc[16];
  #pragma unroll
  for (int s=0;s<16;++s) acc[s] = 0.f;
  for (int v=0; v<16; ++v){
    const float* wp = crow + v*16;
    float w[16];
    #pragma unroll
    for (int k=0;k<16;++k) w[k] = wp[k];
    const float c0 = crow[256+v] + bvd;
    #pragma unroll
    for (int s=0;s<16;++s){
      float dot = c0;
      #pragma unroll
      for (int k=0;k<16;++k) dot += w[k]*patchL[s][v][k];
      acc[s] += attnL[s][hh][v]*dot;
    }
  }
  #pragma unroll
  for (int s=0;s<16;++s) ctx[(size_t)(l0+s)*D_ + d] = f2bu(acc[s]);
}

// ---------------------------------------------------------------------------
extern "C" void kernel_launch(void* const* d_in, const int* in_sizes, int n_in,
                              void* d_out, int out_size, void* d_ws, size_t ws_size,
                              hipStream_t stream){
  const float* x      = (const float*)d_in[0];
  const float* proj_w = (const float*)d_in[1];
  const float* proj_b = (const float*)d_in[2];
  const float* ce     = (const float*)d_in[3];
  const float* pe     = (const float*)d_in[4];
  const float* cq     = (const float*)d_in[5];
  const float* wq     = (const float*)d_in[6];
  const float* wk     = (const float*)d_in[7];
  const float* wv     = (const float*)d_in[8];
  const float* bq     = (const float*)d_in[9];
  // bk (d_in[10]) cancels in softmax
  const float* bv     = (const float*)d_in[11];
  const float* wo     = (const float*)d_in[12];
  const float* bo     = (const float*)d_in[13];
  float* out = (float*)d_out;

  // workspace — peak 8,744,960 B (< proven 9,589,760)
  // R1 region (69,632..4,263,936) time-shared: Ab (steps 3-6) -> wvTb (7-8) -> ctxb (loop)
  char* base = (char*)d_ws;
  float*          q    = (float*)(base + 0);                  // 4 KB
  float*          qwk  = (float*)(base + 4096);               // 64 KB
  unsigned short* Ab   = (unsigned short*)(base + 69632);     // [1152][1024] bf16, 2.36 MB
  unsigned short* wvTb = (unsigned short*)(base + 69632);     // [1024][1024] bf16 (after Ab dead)
  unsigned short* ctxb = (unsigned short*)(base + 69632);     // [2048][1024] bf16 (after wvTb dead)
  unsigned short* Btb  = (unsigned short*)(base + 4263936);   // [384][1024] bf16, 0.79 MB
  float*          Cbig = (float*)(base + 5050368);            // [1040][384] fp32, 1.6 MB
  unsigned short* W2b  = (unsigned short*)(base + 6647808);   // [1024][1024] bf16, 2 MB -> 8,744,960

  k_q   <<<4,  256, 0, stream>>>(cq, wq, bq, q);
  k_qwk <<<64, 256, 0, stream>>>(q, wk, qwk);
  k_cvt <<<1024, 256, 0, stream>>>(wv, Ab, 1.0f);                  // A rows 0..1023
  k_cvt <<<16,   256, 0, stream>>>(qwk, Ab + (size_t)1024*D_, 0.125f); // A rows 1024..1039
  k_tpB <<<dim3(16,16), 256, 0, stream>>>(proj_w, proj_b, ce, Btb);
  k_gemm_big<<<dim3(3,9), 256, 0, stream>>>(Ab, Btb, Cbig, 1040);
  k_tc  <<<dim3(16,16), 256, 0, stream>>>(wv, wvTb);
  k_gemm_fb<<<dim3(8,8), 256, 0, stream>>>(wo, wvTb, W2b);         // W2 = wo·wv
  for (int b = 0; b < 2; ++b){
    k_fused3<<<512, 256, 0, stream>>>(x, b, Cbig, bv, ctxb);
    // out_b = ctx0·wo^T + pe·W2^T + bo
    k_gemm_cat3<<<dim3(8,16), 256, 0, stream>>>(ctxb, wo, pe, W2b, bo, out + (size_t)b*L_*D_);
  }
}

// Round 6
// 304.001 us; speedup vs baseline: 1.4016x; 1.4016x over previous
//
#include <hip/hip_runtime.h>
#include <hip/hip_bf16.h>

using bf16 = __hip_bfloat16;
using bf16x8 = __attribute__((ext_vector_type(8))) short;
using f32x4  = __attribute__((ext_vector_type(4))) float;

__device__ inline unsigned short f2bu(float f){ bf16 h = __float2bfloat16(f); return *(unsigned short*)&h; }
__device__ inline void async_cp16(const void* g, void* l){
  __builtin_amdgcn_global_load_lds((const __attribute__((address_space(1))) void*)g,
                                   (__attribute__((address_space(3))) void*)l, 16, 0, 0);
}

constexpr int D_ = 1024, L_ = 2048;
constexpr int CN = 384;   // Cbig row stride (floats)

// ---------------------------------------------------------------------------
__global__ __launch_bounds__(256) void k_qinit(const float* __restrict__ bq, float* __restrict__ q){
  int e = blockIdx.x*256 + threadIdx.x;
  q[e] = bq[e];
}

// q[e] += sum_d cq[d]*wq[e,d] ; grid 256 = (ec 0..15, ds 0..15), wave-reduce + atomic
__global__ __launch_bounds__(256) void k_q2(const float* __restrict__ cq, const float* __restrict__ wq,
                                            float* __restrict__ q){
  const int ec = blockIdx.x >> 4, ds = blockIdx.x & 15;
  const int w = threadIdx.x >> 6, lane = threadIdx.x & 63;
  const int d = ds*64 + lane;
  const float c = cq[d];
  const int e0 = ec*64 + w*16;
  #pragma unroll
  for (int j=0;j<16;++j){
    float p = c*wq[(size_t)(e0+j)*D_ + d];
    #pragma unroll
    for (int m=32;m>=1;m>>=1) p += __shfl_xor(p, m, 64);
    if (lane==0) atomicAdd(&q[e0+j], p);
  }
}

// qwk[hh][d] = sum_e q[hh*64+e]*wk[hh*64+e,d] ; grid 256 = (hh, dq), LDS reduce over e-groups
__global__ __launch_bounds__(256) void k_qwk2(const float* __restrict__ q, const float* __restrict__ wk,
                                              float* __restrict__ qwk){
  __shared__ float red[4][64];
  const int hh = blockIdx.x >> 4, dq = blockIdx.x & 15;
  const int eg = threadIdx.x >> 6, dl = threadIdx.x & 63;
  const int d = dq*64 + dl;
  float s = 0.f;
  #pragma unroll
  for (int j=0;j<16;++j){
    int e = hh*64 + eg*16 + j;
    s += q[e]*wk[(size_t)e*D_ + d];
  }
  red[eg][dl] = s;
  __syncthreads();
  if (eg==0)
    qwk[hh*D_ + d] = (red[0][dl]+red[1][dl]) + (red[2][dl]+red[3][dl]);
}

// fp32 -> bf16 bulk convert (4 elems/thread), optional scale
__global__ __launch_bounds__(256) void k_cvt(const float* __restrict__ in, unsigned short* __restrict__ outp,
                                             float scale){
  int i = blockIdx.x*256 + threadIdx.x;
  float4 v = *(const float4*)(in + (size_t)4*i);
  *(ushort4*)(outp + (size_t)4*i) = make_ushort4(f2bu(v.x*scale), f2bu(v.y*scale),
                                                 f2bu(v.z*scale), f2bu(v.w*scale));
}

// Build Btb [384][1024] bf16: rows v*16+k = proj_w[v][dd][k] (transposed);
// rows 256+v = proj_b[v]+ce[v]. grid (16 ddchunk, 16 v).
__global__ __launch_bounds__(256) void k_tpB(const float* __restrict__ proj_w, const float* __restrict__ proj_b,
                                             const float* __restrict__ ce, unsigned short* __restrict__ Btb){
  __shared__ float t[64][17];
  const int tid = threadIdx.x;
  const int v = blockIdx.y, dd0 = blockIdx.x*64;
  { const int r = tid >> 2, kq = tid & 3;
    float4 a = *(const float4*)(proj_w + ((size_t)(v*D_ + dd0 + r))*16 + kq*4);
    t[r][kq*4+0]=a.x; t[r][kq*4+1]=a.y; t[r][kq*4+2]=a.z; t[r][kq*4+3]=a.w; }
  __syncthreads();
  { const int k = tid >> 4, c0 = (tid & 15)*4;
    ushort4 o = make_ushort4(f2bu(t[c0+0][k]), f2bu(t[c0+1][k]), f2bu(t[c0+2][k]), f2bu(t[c0+3][k]));
    *(ushort4*)(Btb + (size_t)(v*16+k)*D_ + dd0 + c0) = o; }
  if (tid < 16){
    const int c0 = tid*4;
    float4 pb = *(const float4*)(proj_b + v*D_ + dd0 + c0);
    float4 cc = *(const float4*)(ce     + v*D_ + dd0 + c0);
    ushort4 o = make_ushort4(f2bu(pb.x+cc.x), f2bu(pb.y+cc.y), f2bu(pb.z+cc.z), f2bu(pb.w+cc.w));
    *(ushort4*)(Btb + (size_t)(256+v)*D_ + dd0 + c0) = o;
  }
}

// ---------------------------------------------------------------------------
// unified GEMM: C fp32 [M][ldc] = A[M][K] * Bt[N][K]^T (+bias)
// BM=64, BN=128, BK=32; 4 waves, wave tile 32x64 (2x4 frags).
// bf16-A path uses global_load_lds(16B); fp32-A path converts via VGPR+ds_write.
// LDS layout: row-major [row][32] with kq XOR-swizzle ((row>>1)&3) -> <=2-way banks.
template<bool AFP32, bool BIAS>
__global__ __launch_bounds__(256) void k_gemm(const void* __restrict__ Av,
                                              const unsigned short* __restrict__ Bt,
                                              const float* __restrict__ bias,
                                              float* __restrict__ C,
                                              int K, int ldc, int Mvalid){
  __shared__ unsigned short As[64*32];
  __shared__ unsigned short Bs[128*32];
  const int tid = threadIdx.x;
  const int wave = tid >> 6, lane = tid & 63;
  const int wm = wave & 1, wn = wave >> 1;
  const int m0 = blockIdx.y*64, n0 = blockIdx.x*128;
  const int lm = lane & 15, kg4 = lane >> 4;
  f32x4 acc[2][4];
  #pragma unroll
  for (int mf=0;mf<2;++mf)
    #pragma unroll
    for (int nf=0;nf<4;++nf)
      acc[mf][nf] = (f32x4){0.f,0.f,0.f,0.f};
  const unsigned short* Abf = (const unsigned short*)Av;
  const float* Afp = (const float*)Av;
  const int arow = tid >> 2;
  const int akq  = (tid & 3) ^ ((tid >> 3) & 3);   // global k-chunk this thread stages
  for (int k0=0; k0<K; k0+=32){
    if (!AFP32){
      async_cp16(Abf + (size_t)(m0+arow)*K + k0 + akq*8, &As[tid*8]);
    } else {
      const float* gp = Afp + (size_t)(m0+arow)*K + k0 + akq*8;
      float4 a0 = *(const float4*)gp, a1 = *(const float4*)(gp+4);
      *(ushort4*)(&As[tid*8])   = make_ushort4(f2bu(a0.x),f2bu(a0.y),f2bu(a0.z),f2bu(a0.w));
      *(ushort4*)(&As[tid*8+4]) = make_ushort4(f2bu(a1.x),f2bu(a1.y),f2bu(a1.z),f2bu(a1.w));
    }
    #pragma unroll
    for (int i=0;i<2;++i){
      int idx = i*256 + tid;
      int col = idx >> 2, kqg = (idx & 3) ^ ((idx >> 3) & 3);
      async_cp16(Bt + (size_t)(n0+col)*K + k0 + kqg*8, &Bs[idx*8]);
    }
    __syncthreads();
    bf16x8 af[2], bfr[4];
    #pragma unroll
    for (int f=0;f<2;++f){
      int row = wm*32 + f*16 + lm;
      af[f] = *(const bf16x8*)(&As[row*32 + ((kg4 ^ (row>>1)) & 3)*8 + (kg4 & ~3)*8]);
    }
    #pragma unroll
    for (int f=0;f<4;++f){
      int colr = wn*64 + f*16 + lm;
      bfr[f] = *(const bf16x8*)(&Bs[colr*32 + ((kg4 ^ (colr>>1)) & 3)*8 + (kg4 & ~3)*8]);
    }
    #pragma unroll
    for (int mf=0;mf<2;++mf)
      #pragma unroll
      for (int nf=0;nf<4;++nf)
        acc[mf][nf] = __builtin_amdgcn_mfma_f32_16x16x32_bf16(af[mf], bfr[nf], acc[mf][nf], 0,0,0);
    __syncthreads();
  }
  #pragma unroll
  for (int nf=0;nf<4;++nf){
    int col = n0 + wn*64 + nf*16 + lm;
    float bval = BIAS ? bias[col] : 0.f;
    #pragma unroll
    for (int mf=0;mf<2;++mf){
      #pragma unroll
      for (int r=0;r<4;++r){
        int row = m0 + wm*32 + mf*16 + kg4*4 + r;   // C: col=lane&15, row=(lane>>4)*4+reg
        if (row < Mvalid) C[(size_t)row*ldc + col] = acc[mf][nf][r] + bval;
      }
    }
  }
}

// ---------------------------------------------------------------------------
// fused per-batch: patches -> scores -> softmax -> ctx = P2 + sum_v attn*(...)  (bf16 out)
// grid 512 = 128 site-groups (16 sites) x 4 d-chunks (256 d)
__global__ __launch_bounds__(256) void k_fused3(const float* __restrict__ x, int bb,
                                                const float* __restrict__ Cbig, const float* __restrict__ bv,
                                                const float* __restrict__ P2,
                                                unsigned short* __restrict__ ctx){
  __shared__ float patchL[16][16][16];  // [s][v][k]
  __shared__ float attnL[16][16][16];   // [s][hh][v]
  const int tid = threadIdx.x;
  const int sg = blockIdx.x >> 2;
  const int dc = blockIdx.x & 3;
  { // phase A: load patches (thread = (s, v))
    const int s = tid >> 4, v = tid & 15;
    const int l = sg*16 + s;
    const int hi = l >> 6, wi = l & 63;
    const float* xp = x + ((size_t)((bb*16+v)*128 + hi*4)*256 + wi*4);
    #pragma unroll
    for (int pi=0; pi<4; ++pi){
      float4 r = *(const float4*)(xp + pi*256);
      patchL[s][v][pi*4+0] = r.x; patchL[s][v][pi*4+1] = r.y;
      patchL[s][v][pi*4+2] = r.z; patchL[s][v][pi*4+3] = r.w;
    }
  }
  __syncthreads();
  { // phase B: scores + softmax (thread = (s, hh)); v-const terms cancel in softmax
    const int s = tid >> 4, hh = tid & 15;
    const float* qrow = Cbig + (size_t)(1024+hh)*CN;
    float sc[16];
    #pragma unroll
    for (int v=0; v<16; ++v){
      float a = qrow[256+v];
      const float* qp = qrow + v*16;
      #pragma unroll
      for (int k=0;k<16;++k) a += qp[k]*patchL[s][v][k];
      sc[v] = a;
    }
    float mx = sc[0];
    #pragma unroll
    for (int v=1;v<16;++v) mx = fmaxf(mx, sc[v]);
    float sum = 0.f;
    #pragma unroll
    for (int v=0;v<16;++v){ sc[v] = __expf(sc[v]-mx); sum += sc[v]; }
    float inv = 1.f/sum;
    #pragma unroll
    for (int v=0;v<16;++v) attnL[s][hh][v] = sc[v]*inv;
  }
  __syncthreads();
  // phase C: ctx[s][d] = P2[l][d] + sum_v attn[s,hh,v]*(wvp[v,d,:]·patch[s,v,:] + wvc[v,d])
  const int d = dc*256 + tid;
  const int hh = d >> 6;
  const int l0 = sg*16;
  const float* crow = Cbig + (size_t)d*CN;
  const float bvd = bv[d];
  float acc[16];
  #pragma unroll
  for (int s=0;s<16;++s) acc[s] = P2[(size_t)(l0+s)*D_ + d];
  for (int v=0; v<16; ++v){
    const float* wp = crow + v*16;
    float w[16];
    #pragma unroll
    for (int k=0;k<16;++k) w[k] = wp[k];
    const float c0 = crow[256+v] + bvd;
    #pragma unroll
    for (int s=0;s<16;++s){
      float dot = c0;
      #pragma unroll
      for (int k=0;k<16;++k) dot += w[k]*patchL[s][v][k];
      acc[s] += attnL[s][hh][v]*dot;
    }
  }
  #pragma unroll
  for (int s=0;s<16;++s) ctx[(size_t)(l0+s)*D_ + d] = f2bu(acc[s]);
}

// ---------------------------------------------------------------------------
extern "C" void kernel_launch(void* const* d_in, const int* in_sizes, int n_in,
                              void* d_out, int out_size, void* d_ws, size_t ws_size,
                              hipStream_t stream){
  const float* x      = (const float*)d_in[0];
  const float* proj_w = (const float*)d_in[1];
  const float* proj_b = (const float*)d_in[2];
  const float* ce     = (const float*)d_in[3];
  const float* pe     = (const float*)d_in[4];
  const float* cq     = (const float*)d_in[5];
  const float* wq     = (const float*)d_in[6];
  const float* wk     = (const float*)d_in[7];
  const float* wv     = (const float*)d_in[8];
  const float* bq     = (const float*)d_in[9];
  // bk (d_in[10]) cancels in softmax
  const float* bv     = (const float*)d_in[11];
  const float* wo     = (const float*)d_in[12];
  const float* bo     = (const float*)d_in[13];
  float* out = (float*)d_out;

  // workspace — peak 7,958,528 B (< proven 9,589,760)
  char* base = (char*)d_ws;
  float*          q    = (float*)(base);                         // 4 KB
  float*          qwk  = (float*)(base + 4096);                  // 64 KB -> 69,632
  unsigned short* ctxb = (unsigned short*)(base + 69632);        // [2048][1024] bf16, 4 MB -> 4,263,936
  unsigned short* Ab   = (unsigned short*)(base + 69632);        // [1152][1024] bf16 (overlaps ctx, dead before fused3)
  unsigned short* Btb  = (unsigned short*)(base + 69632 + 2359296); // [384][1024] bf16 (overlaps ctx)
  float*          Cbig = (float*)(base + 4263936);               // [1040][384] fp32 -> 5,861,376
  unsigned short* wo_b = (unsigned short*)(base + 5861376);      // [1024][1024] bf16 -> 7,958,528
  float*          P2   = out + (size_t)L_*D_;                    // pe·wv^T staged in d_out batch-1 half

  k_qinit<<<4,   256, 0, stream>>>(bq, q);
  k_q2   <<<256, 256, 0, stream>>>(cq, wq, q);
  k_qwk2 <<<256, 256, 0, stream>>>(q, wk, qwk);
  k_cvt  <<<1024,256, 0, stream>>>(wv, Ab, 1.0f);                       // Ab rows 0..1023 = bf16(wv)
  k_cvt  <<<16,  256, 0, stream>>>(qwk, Ab + (size_t)1024*D_, 0.125f);  // rows 1024..1039 = qwk/8
  k_cvt  <<<1024,256, 0, stream>>>(wo, wo_b, 1.0f);
  k_tpB  <<<dim3(16,16), 256, 0, stream>>>(proj_w, proj_b, ce, Btb);
  // Cbig = [wv; qwk/8] · [proj_w^T; pb+ce]^T   (rows>=1040 masked; pad A rows read but unused)
  k_gemm<false,false><<<dim3(3,17), 256, 0, stream>>>(Ab, Btb, nullptr, Cbig, 1024, CN, 1040);
  // P2 = pe · wv^T  (A fp32 staged, Bt = bf16(wv))
  k_gemm<true,false><<<dim3(8,32), 256, 0, stream>>>(pe, Ab, nullptr, P2, 1024, 1024, 2048);
  for (int b = 0; b < 2; ++b){
    k_fused3<<<512, 256, 0, stream>>>(x, b, Cbig, bv, P2, ctxb);
    // out_b = ctx·wo^T + bo   (K=1024, all-bf16)
    k_gemm<false,true><<<dim3(8,32), 256, 0, stream>>>(ctxb, wo_b, bo, out + (size_t)b*L_*D_, 1024, 1024, 2048);
  }
}